// Round 1
// baseline (24472.780 us; speedup 1.0000x reference)
//
#include <hip/hip_runtime.h>
#include <stdint.h>

#define NB    256   // batch / segments
#define CIN   128   // input channels
#define HID   256   // hidden
#define TST   256   // only first 256 timesteps matter for the output
#define NCLS  400

// ---- workspace layout (bytes) ----
#define WS_SUMS   0u                       // 256*128*4   = 131072
#define WS_HBUF   131072u                  // 2*256*256*4 = 524288  (double-buffered h)
#define WS_C0     655360u                  // 256*256*4   = 262144
#define WS_CTRS   917504u                  // 64*4 group barrier counters
#define WS_PP     1048576u                 // 256*64*4*64*4 = 16777216 masked partial sums
// total ~17.8 MB

__device__ __forceinline__ float sigm(float v) { return 1.0f / (1.0f + __expf(-v)); }
__device__ __forceinline__ float tanh_(float v) {
  v = fminf(fmaxf(v, -15.0f), 15.0f);
  const float e = __expf(2.0f * v);
  return (e - 1.0f) / (e + 1.0f);
}

// ---------------- segment sums (the "input_means" that are really sums) ----------------
__global__ void k_segsum(const float* __restrict__ x, const int* __restrict__ lens,
                         float* __restrict__ sums) {
  const int b = blockIdx.x, t = threadIdx.x;
  __shared__ int   s_l[NB];
  __shared__ int   s_red[256];
  __shared__ float s_f[CIN];
  s_l[t] = lens[t];
  __syncthreads();
  int part = 0;
  for (int i = t; i < b; i += 256) part += s_l[i];
  s_red[t] = part; __syncthreads();
  for (int k = 128; k > 0; k >>= 1) { if (t < k) s_red[t] += s_red[t + k]; __syncthreads(); }
  const int off = s_red[0];
  const int len = s_l[b];
  const int c = t & 127, half = t >> 7;
  float a = 0.f;
  for (int r = half; r < len; r += 2) a += x[(size_t)(off + r) * CIN + c];
  if (half) s_f[c] = a;
  __syncthreads();
  if (!half) sums[b * CIN + c] = a + s_f[c];
}

// ---------------- h0 = relu(sums@W1h^T)@W2h^T ; c0 likewise ----------------
__global__ void k_init(const float* __restrict__ sums,
                       const float* __restrict__ w1h, const float* __restrict__ w2h,
                       const float* __restrict__ w1c, const float* __restrict__ w2c,
                       float* __restrict__ hbuf, float* __restrict__ c0) {
  const int b = blockIdx.x, t = threadIdx.x;
  __shared__ float s_in[CIN], s_h[CIN], s_c[CIN];
  if (t < CIN) s_in[t] = sums[b * CIN + t];
  __syncthreads();
  {
    const int j = t & 127;
    const float* w = (t < CIN ? w1h : w1c) + j * CIN;
    float a = 0.f;
    #pragma unroll 8
    for (int k = 0; k < CIN; k++) a += s_in[k] * w[k];
    a = fmaxf(a, 0.f);
    if (t < CIN) s_h[j] = a; else s_c[j] = a;
  }
  __syncthreads();
  float ah = 0.f, ac = 0.f;
  const float* wh = w2h + t * CIN;
  const float* wc = w2c + t * CIN;
  #pragma unroll 8
  for (int k = 0; k < CIN; k++) { ah += s_h[k] * wh[k]; ac += s_c[k] * wc[k]; }
  hbuf[b * HID + t] = ah;   // buffer 0 = h_0
  c0[b * HID + t]   = ac;
}

// ---------------- persistent LSTM recurrence ----------------
// 256 blocks = 64 batch-groups (4 batches) x 4 hidden-slice members (64 hid each).
// Thread owns one gate row; W row (384 fp32) lives in registers for all 256 steps.
// blockIdx remap keeps a group's 4 members on one XCD (perf heuristic only).
__launch_bounds__(256, 1)
__global__ void k_lstm(const float* __restrict__ x, const int* __restrict__ lens,
                       const float* __restrict__ Wih, const float* __restrict__ Whh,
                       const float* __restrict__ bih, const float* __restrict__ bhh,
                       const float* __restrict__ c0,
                       float* __restrict__ hbuf, float* __restrict__ pp,
                       int* __restrict__ ctrs) {
  const int p      = blockIdx.x;
  const int xcd    = p & 7;
  const int slot   = p >> 3;          // 0..31
  const int member = slot & 3;        // hidden slice 0..3
  const int gsub   = slot >> 2;       // 0..7
  const int grp    = xcd * 8 + gsub;  // batch group 0..63
  const int bat0   = grp * 4;
  const int hid0   = member * 64;

  const int t  = threadIdx.x;
  const int jl = t & 63, g = t >> 6;          // gate-row role: (gate g, hidden jl)
  const int row = g * HID + hid0 + jl;        // 0..1023
  const int j2 = jl, b2 = g;                  // update role: (hidden j2, batch b2)

  __shared__ float4 s_hx[CIN + HID];          // [k][4 batches]
  __shared__ float4 s_gate[256];              // [g*64+jl] -> 4 batches
  __shared__ float  s_red[256];
  __shared__ int    s_lens[NB];
  __shared__ int    s_off4[4], s_len4[4];

  s_lens[t] = lens[t];
  __syncthreads();
  if (t < 4) {
    int off = 0;
    for (int k = 0; k < bat0 + t; k++) off += s_lens[k];
    s_off4[t] = off;
    s_len4[t] = s_lens[bat0 + t];
  }
  __syncthreads();

  // persistent weights in VGPRs (all indices static after full unroll)
  float wih[CIN];
  {
    const float4* src = (const float4*)(Wih + (size_t)row * CIN);
    #pragma unroll
    for (int k4 = 0; k4 < CIN / 4; k4++) {
      const float4 v = src[k4];
      wih[4*k4+0] = v.x; wih[4*k4+1] = v.y; wih[4*k4+2] = v.z; wih[4*k4+3] = v.w;
    }
  }
  float whh[HID];
  {
    const float4* src = (const float4*)(Whh + (size_t)row * HID);
    #pragma unroll
    for (int k4 = 0; k4 < HID / 4; k4++) {
      const float4 v = src[k4];
      whh[4*k4+0] = v.x; whh[4*k4+1] = v.y; whh[4*k4+2] = v.z; whh[4*k4+3] = v.w;
    }
  }
  const float bias = bih[row] + bhh[row];

  float c_reg = c0[(bat0 + b2) * HID + hid0 + j2];

  float xp[4];
  auto prefx = [&](int s) {
    #pragma unroll
    for (int b = 0; b < 4; b++)
      xp[b] = (t < CIN && s < s_len4[b]) ? x[(size_t)(s_off4[b] + s) * CIN + t] : 0.f;
  };
  auto stage = [&](int s) {
    if (t < CIN) s_hx[t] = make_float4(xp[0], xp[1], xp[2], xp[3]);
    const float* hb = hbuf + (size_t)(s & 1) * NB * HID + t;   // t = k index (0..255)
    float4 hv;
    hv.x = hb[(bat0 + 0) * HID];
    hv.y = hb[(bat0 + 1) * HID];
    hv.z = hb[(bat0 + 2) * HID];
    hv.w = hb[(bat0 + 3) * HID];
    s_hx[CIN + t] = hv;
  };

  prefx(0);
  stage(0);
  __syncthreads();

  for (int s = 0; s < TST; s++) {
    // gates for 4 batches: FMA-bound, LDS float4 broadcast (same addr all lanes)
    float a0 = bias, a1 = bias, a2 = bias, a3 = bias;
    #pragma unroll
    for (int k = 0; k < CIN; k++) {
      const float4 hx = s_hx[k];
      const float w = wih[k];
      a0 = fmaf(w, hx.x, a0); a1 = fmaf(w, hx.y, a1);
      a2 = fmaf(w, hx.z, a2); a3 = fmaf(w, hx.w, a3);
    }
    #pragma unroll
    for (int k = 0; k < HID; k++) {
      const float4 hx = s_hx[CIN + k];
      const float w = whh[k];
      a0 = fmaf(w, hx.x, a0); a1 = fmaf(w, hx.y, a1);
      a2 = fmaf(w, hx.z, a2); a3 = fmaf(w, hx.w, a3);
    }
    s_gate[t] = make_float4(a0, a1, a2, a3);

    if (s < TST - 1) prefx(s + 1);   // x prefetch: drains during update phase
    __syncthreads();

    // i,f,g,o for (hidden j2, batch b2)
    const float vi = ((const float*)&s_gate[  0 + j2])[b2];
    const float vf = ((const float*)&s_gate[ 64 + j2])[b2];
    const float vg = ((const float*)&s_gate[128 + j2])[b2];
    const float vo = ((const float*)&s_gate[192 + j2])[b2];
    c_reg = fmaf(sigm(vf), c_reg, sigm(vi) * tanh_(vg));
    const float h = sigm(vo) * tanh_(c_reg);

    hbuf[(size_t)((s + 1) & 1) * NB * HID + (bat0 + b2) * HID + hid0 + j2] = h;

    // masked partial for output row s: mask is (global batch) < lens[s]
    s_red[b2 * 64 + j2] = (bat0 + b2 < s_lens[s]) ? h : 0.f;
    __syncthreads();
    if (t < 64) {
      const float ps = s_red[t] + s_red[64 + t] + s_red[128 + t] + s_red[192 + t];
      pp[(((size_t)s * 64 + grp) * 4 + member) * 64 + t] = ps;
    }

    if (s == TST - 1) break;

    __threadfence();          // release h stores agent-wide
    __syncthreads();
    if (t == 0) {
      __hip_atomic_fetch_add(ctrs + grp, 1, __ATOMIC_ACQ_REL, __HIP_MEMORY_SCOPE_AGENT);
      const int target = 4 * (s + 1);
      while (__hip_atomic_load(ctrs + grp, __ATOMIC_ACQUIRE, __HIP_MEMORY_SCOPE_AGENT) < target) {}
    }
    __syncthreads();
    __threadfence();          // acquire side for all threads
    stage(s + 1);
    __syncthreads();
  }
}

// ---------------- masked batch-mean + FC ----------------
__global__ void k_out(const float* __restrict__ pp, const int* __restrict__ lens,
                      const float* __restrict__ fcW, const float* __restrict__ fcb,
                      float* __restrict__ out) {
  const int i = blockIdx.x, t = threadIdx.x;
  __shared__ float s_fc[HID];
  const int cnt = min(lens[i], NB);
  const int m = t >> 6, jl = t & 63;
  float a = 0.f;
  const float* base = pp + ((size_t)i * 64 * 4 + m) * 64 + jl;
  #pragma unroll 4
  for (int gg = 0; gg < 64; gg++) a += base[(size_t)gg * 256];
  s_fc[t] = a / (float)cnt;
  __syncthreads();
  for (int n = t; n < NCLS; n += 256) {
    float acc = fcb[n];
    const float4* w4 = (const float4*)(fcW + (size_t)n * HID);
    #pragma unroll 8
    for (int k4 = 0; k4 < HID / 4; k4++) {
      const float4 w = w4[k4];
      acc = fmaf(s_fc[4*k4+0], w.x, acc);
      acc = fmaf(s_fc[4*k4+1], w.y, acc);
      acc = fmaf(s_fc[4*k4+2], w.z, acc);
      acc = fmaf(s_fc[4*k4+3], w.w, acc);
    }
    out[(size_t)i * NCLS + n] = acc;
  }
}

extern "C" void kernel_launch(void* const* d_in, const int* in_sizes, int n_in,
                              void* d_out, int out_size, void* d_ws, size_t ws_size,
                              hipStream_t stream) {
  const float* x    = (const float*)d_in[0];
  const int*   lens = (const int*)  d_in[1];
  const float* Wih  = (const float*)d_in[2];
  const float* Whh  = (const float*)d_in[3];
  const float* bih  = (const float*)d_in[4];
  const float* bhh  = (const float*)d_in[5];
  const float* w1h  = (const float*)d_in[6];
  const float* w2h  = (const float*)d_in[7];
  const float* w1c  = (const float*)d_in[8];
  const float* w2c  = (const float*)d_in[9];
  const float* fcW  = (const float*)d_in[10];
  const float* fcb  = (const float*)d_in[11];
  float* out = (float*)d_out;

  char* ws = (char*)d_ws;
  float* sums = (float*)(ws + WS_SUMS);
  float* hbuf = (float*)(ws + WS_HBUF);
  float* c0   = (float*)(ws + WS_C0);
  int*   ctrs = (int*)  (ws + WS_CTRS);
  float* pp   = (float*)(ws + WS_PP);

  hipMemsetAsync(ctrs, 0, 64 * sizeof(int), stream);   // barrier counters must be 0 every call
  k_segsum<<<NB, 256, 0, stream>>>(x, lens, sums);
  k_init  <<<NB, 256, 0, stream>>>(sums, w1h, w2h, w1c, w2c, hbuf, c0);
  k_lstm  <<<NB, 256, 0, stream>>>(x, lens, Wih, Whh, bih, bhh, c0, hbuf, pp, ctrs);
  k_out   <<<NB, 256, 0, stream>>>(pp, lens, fcW, fcb, out);
}

// Round 2
// 21119.598 us; speedup vs baseline: 1.1588x; 1.1588x over previous
//
#include <hip/hip_runtime.h>
#include <stdint.h>

#define NB    256   // batch / segments
#define CIN   128   // input channels
#define HID   256   // hidden
#define TST   256   // only first 256 timesteps matter for the output
#define NCLS  400

#define GRPS  32    // batch groups
#define MEMB  8     // blocks per group (hidden-slice members)
#define BPG   8     // batches per group
#define RPB   128   // gate-rows per block (4 gates x 32 hid)
#define HPB   32    // hidden units per block

// ---- workspace layout (bytes) ----
#define WS_SUMS   0u                       // 256*128*4   = 131072
#define WS_HBUF   131072u                  // 2*256*256*4 = 524288  (double-buffered h)
#define WS_C0     655360u                  // 256*256*4   = 262144
#define WS_CTRS   917504u                  // 32*4 group barrier counters
#define WS_PP     1048576u                 // 256*32*8*32*4 = 8388608 masked partial sums

__device__ __forceinline__ float sigm(float v) { return 1.0f / (1.0f + __expf(-v)); }
__device__ __forceinline__ float tanh_(float v) {
  v = fminf(fmaxf(v, -15.0f), 15.0f);
  const float e = __expf(2.0f * v);
  return (e - 1.0f) / (e + 1.0f);
}

// ---------------- segment sums (the "input_means" that are really sums) ----------------
__global__ void k_segsum(const float* __restrict__ x, const int* __restrict__ lens,
                         float* __restrict__ sums) {
  const int b = blockIdx.x, t = threadIdx.x;
  __shared__ int   s_l[NB];
  __shared__ int   s_red[256];
  __shared__ float s_f[CIN];
  s_l[t] = lens[t];
  __syncthreads();
  int part = 0;
  for (int i = t; i < b; i += 256) part += s_l[i];
  s_red[t] = part; __syncthreads();
  for (int k = 128; k > 0; k >>= 1) { if (t < k) s_red[t] += s_red[t + k]; __syncthreads(); }
  const int off = s_red[0];
  const int len = s_l[b];
  const int c = t & 127, half = t >> 7;
  float a = 0.f;
  for (int r = half; r < len; r += 2) a += x[(size_t)(off + r) * CIN + c];
  if (half) s_f[c] = a;
  __syncthreads();
  if (!half) sums[b * CIN + c] = a + s_f[c];
}

// ---------------- h0 = relu(sums@W1h^T)@W2h^T ; c0 likewise ----------------
__global__ void k_init(const float* __restrict__ sums,
                       const float* __restrict__ w1h, const float* __restrict__ w2h,
                       const float* __restrict__ w1c, const float* __restrict__ w2c,
                       float* __restrict__ hbuf, float* __restrict__ c0) {
  const int b = blockIdx.x, t = threadIdx.x;
  __shared__ float s_in[CIN], s_h[CIN], s_c[CIN];
  if (t < CIN) s_in[t] = sums[b * CIN + t];
  __syncthreads();
  {
    const int j = t & 127;
    const float* w = (t < CIN ? w1h : w1c) + j * CIN;
    float a = 0.f;
    #pragma unroll 8
    for (int k = 0; k < CIN; k++) a += s_in[k] * w[k];
    a = fmaxf(a, 0.f);
    if (t < CIN) s_h[j] = a; else s_c[j] = a;
  }
  __syncthreads();
  float ah = 0.f, ac = 0.f;
  const float* wh = w2h + t * CIN;
  const float* wc = w2c + t * CIN;
  #pragma unroll 8
  for (int k = 0; k < CIN; k++) { ah += s_h[k] * wh[k]; ac += s_c[k] * wc[k]; }
  hbuf[b * HID + t] = ah;   // buffer 0 = h_0
  c0[b * HID + t]   = ac;
}

// ---------------- persistent LSTM recurrence ----------------
// 256 blocks = 32 batch-groups (8 batches) x 8 hidden-slice members (32 hid = 128 rows).
// Thread = (gate-row, K-half): 192 weight floats in VGPRs (fits under the 256-VGPR arch cap;
// 384/thread last round spilled to scratch -> 9.6 GB FETCH, 45x slowdown).
// Group members at blockIdx stride 32 (32%8==0 -> same XCD under round-robin dispatch).
__launch_bounds__(256, 1)
__global__ void k_lstm(const float* __restrict__ x, const int* __restrict__ lens,
                       const float* __restrict__ Wih, const float* __restrict__ Whh,
                       const float* __restrict__ bih, const float* __restrict__ bhh,
                       const float* __restrict__ c0,
                       float* __restrict__ hbuf, float* __restrict__ pp,
                       int* __restrict__ ctrs) {
  const int p    = blockIdx.x;
  const int m    = p >> 5;            // member 0..7 (hidden slice)
  const int grp  = p & 31;            // batch group 0..31
  const int bat0 = grp * BPG;
  const int hid0 = m * HPB;

  const int t  = threadIdx.x;
  const int r  = t & 127;             // local gate-row 0..127
  const int kh = t >> 7;              // K-half
  const int gidx = r >> 5, j = r & 31;
  const int row = gidx * HID + hid0 + j;   // global gate row 0..1023

  // update role: (hidden j2, batch b2)
  const int j2 = t & 31, b2 = (t >> 5) & 7;
  // x staging role: (channel cch, batch-half bh)
  const int cch = t & 127, bh = t >> 7;

  __shared__ float s_hx[(CIN + HID) * BPG];   // [384 k][8 b] = 12 KB
  __shared__ float s_part[2 * RPB * BPG];     // 8 KB K-half partials
  __shared__ float s_gate[RPB * BPG];         // 4 KB
  __shared__ float s_red[256];
  __shared__ int   s_lens[NB];
  __shared__ int   s_off[BPG], s_len[BPG];

  s_lens[t] = lens[t];
  __syncthreads();
  if (t < BPG) {
    int off = 0;
    for (int k = 0; k < bat0 + t; k++) off += s_lens[k];
    s_off[t] = off;
    s_len[t] = s_lens[bat0 + t];
  }
  __syncthreads();

  // ---- persistent weights: 192 fp32 in VGPRs (all indices static after unroll) ----
  float w[192];
  if (kh == 0) {  // W_ih row (128) ++ W_hh row [0:64)
    const float4* a = (const float4*)(Wih + (size_t)row * CIN);
    #pragma unroll
    for (int q = 0; q < 32; q++) {
      const float4 v = a[q];
      w[4*q+0] = v.x; w[4*q+1] = v.y; w[4*q+2] = v.z; w[4*q+3] = v.w;
    }
    const float4* b = (const float4*)(Whh + (size_t)row * HID);
    #pragma unroll
    for (int q = 0; q < 16; q++) {
      const float4 v = b[q];
      w[128+4*q+0] = v.x; w[128+4*q+1] = v.y; w[128+4*q+2] = v.z; w[128+4*q+3] = v.w;
    }
  } else {        // W_hh row [64:256)
    const float4* b = (const float4*)(Whh + (size_t)row * HID + 64);
    #pragma unroll
    for (int q = 0; q < 48; q++) {
      const float4 v = b[q];
      w[4*q+0] = v.x; w[4*q+1] = v.y; w[4*q+2] = v.z; w[4*q+3] = v.w;
    }
  }
  const float bias = (kh == 0) ? (bih[row] + bhh[row]) : 0.f;
  const int ks = kh ? 192 : 0;

  float c_reg = c0[(size_t)(bat0 + b2) * HID + hid0 + j2];

  float xp[4];
  auto prefx = [&](int s) {
    #pragma unroll
    for (int b = 0; b < 4; b++) {
      const int gb = bh * 4 + b;
      xp[b] = (s < s_len[gb]) ? x[(size_t)(s_off[gb] + s) * CIN + cch] : 0.f;
    }
  };
  auto stage = [&](int s) {
    *(float4*)&s_hx[cch * BPG + bh * 4] = make_float4(xp[0], xp[1], xp[2], xp[3]);
    const float* hb = hbuf + (size_t)(s & 1) * NB * HID + t;   // t = hidden k index
    float hv[8];
    #pragma unroll
    for (int b = 0; b < 8; b++) hv[b] = hb[(size_t)(bat0 + b) * HID];
    *(float4*)&s_hx[(CIN + t) * BPG + 0] = make_float4(hv[0], hv[1], hv[2], hv[3]);
    *(float4*)&s_hx[(CIN + t) * BPG + 4] = make_float4(hv[4], hv[5], hv[6], hv[7]);
  };

  prefx(0);
  stage(0);
  __syncthreads();

  for (int s = 0; s < TST; s++) {
    // ---- gate partials: 192 K x 8 batches, LDS rows are wave-uniform broadcasts ----
    float a0 = bias, a1 = bias, a2 = bias, a3 = bias;
    float a4 = bias, a5 = bias, a6 = bias, a7 = bias;
    const float4* hx4 = (const float4*)s_hx;
    #pragma unroll
    for (int k = 0; k < 192; k++) {
      const float4 lo = hx4[(ks + k) * 2 + 0];
      const float4 hi = hx4[(ks + k) * 2 + 1];
      const float ww = w[k];
      a0 = fmaf(ww, lo.x, a0); a1 = fmaf(ww, lo.y, a1);
      a2 = fmaf(ww, lo.z, a2); a3 = fmaf(ww, lo.w, a3);
      a4 = fmaf(ww, hi.x, a4); a5 = fmaf(ww, hi.y, a5);
      a6 = fmaf(ww, hi.z, a6); a7 = fmaf(ww, hi.w, a7);
    }
    *(float4*)&s_part[(kh * RPB + r) * BPG + 0] = make_float4(a0, a1, a2, a3);
    *(float4*)&s_part[(kh * RPB + r) * BPG + 4] = make_float4(a4, a5, a6, a7);

    if (s < TST - 1) prefx(s + 1);   // global x loads drain during reduce/update
    __syncthreads();

    // ---- K-half reduction: thread handles (row t&127, batch-quad t>>7) ----
    {
      const int r2 = t & 127, q = t >> 7;
      const float4 p0 = *(const float4*)&s_part[(0 * RPB + r2) * BPG + q * 4];
      const float4 p1 = *(const float4*)&s_part[(1 * RPB + r2) * BPG + q * 4];
      *(float4*)&s_gate[r2 * BPG + q * 4] =
          make_float4(p0.x + p1.x, p0.y + p1.y, p0.z + p1.z, p0.w + p1.w);
    }
    __syncthreads();

    // ---- LSTM update for (hidden j2, batch b2) ----
    const float vi = s_gate[(0 * HPB + j2) * BPG + b2];
    const float vf = s_gate[(1 * HPB + j2) * BPG + b2];
    const float vg = s_gate[(2 * HPB + j2) * BPG + b2];
    const float vo = s_gate[(3 * HPB + j2) * BPG + b2];
    c_reg = fmaf(sigm(vf), c_reg, sigm(vi) * tanh_(vg));
    const float h = sigm(vo) * tanh_(c_reg);

    hbuf[(size_t)((s + 1) & 1) * NB * HID + (size_t)(bat0 + b2) * HID + hid0 + j2] = h;
    s_red[b2 * HPB + j2] = (bat0 + b2 < s_lens[s]) ? h : 0.f;

    __threadfence();            // release h stores agent-wide
    __syncthreads();

    // masked partial for output row s (overlaps the barrier spin below)
    if (t >= 32 && t < 64) {
      const int jl = t - 32;
      float ps = 0.f;
      #pragma unroll
      for (int b = 0; b < 8; b++) ps += s_red[b * HPB + jl];
      pp[(((size_t)s * GRPS + grp) * MEMB + m) * HPB + jl] = ps;
    }

    if (s == TST - 1) break;

    if (t == 0) {
      __hip_atomic_fetch_add(ctrs + grp, 1, __ATOMIC_ACQ_REL, __HIP_MEMORY_SCOPE_AGENT);
      const int target = MEMB * (s + 1);
      while (__hip_atomic_load(ctrs + grp, __ATOMIC_ACQUIRE, __HIP_MEMORY_SCOPE_AGENT) < target) {}
    }
    __syncthreads();
    __threadfence();            // acquire side for all threads
    stage(s + 1);
    __syncthreads();
  }
}

// ---------------- masked batch-mean + FC ----------------
__global__ void k_out(const float* __restrict__ pp, const int* __restrict__ lens,
                      const float* __restrict__ fcW, const float* __restrict__ fcb,
                      float* __restrict__ out) {
  const int i = blockIdx.x, t = threadIdx.x;
  __shared__ float s_fc[HID];
  const int cnt = min(lens[i], NB);
  const int m = t >> 5, jl = t & 31;             // hid = t
  float a = 0.f;
  const float* base = pp + ((size_t)i * GRPS * MEMB + m) * HPB + jl;
  #pragma unroll 4
  for (int g = 0; g < GRPS; g++) a += base[(size_t)g * MEMB * HPB];
  s_fc[t] = a / (float)cnt;
  __syncthreads();
  for (int n = t; n < NCLS; n += 256) {
    float acc = fcb[n];
    const float4* w4 = (const float4*)(fcW + (size_t)n * HID);
    #pragma unroll 8
    for (int k4 = 0; k4 < HID / 4; k4++) {
      const float4 w = w4[k4];
      acc = fmaf(s_fc[4*k4+0], w.x, acc);
      acc = fmaf(s_fc[4*k4+1], w.y, acc);
      acc = fmaf(s_fc[4*k4+2], w.z, acc);
      acc = fmaf(s_fc[4*k4+3], w.w, acc);
    }
    out[(size_t)i * NCLS + n] = acc;
  }
}

extern "C" void kernel_launch(void* const* d_in, const int* in_sizes, int n_in,
                              void* d_out, int out_size, void* d_ws, size_t ws_size,
                              hipStream_t stream) {
  const float* x    = (const float*)d_in[0];
  const int*   lens = (const int*)  d_in[1];
  const float* Wih  = (const float*)d_in[2];
  const float* Whh  = (const float*)d_in[3];
  const float* bih  = (const float*)d_in[4];
  const float* bhh  = (const float*)d_in[5];
  const float* w1h  = (const float*)d_in[6];
  const float* w2h  = (const float*)d_in[7];
  const float* w1c  = (const float*)d_in[8];
  const float* w2c  = (const float*)d_in[9];
  const float* fcW  = (const float*)d_in[10];
  const float* fcb  = (const float*)d_in[11];
  float* out = (float*)d_out;

  char* ws = (char*)d_ws;
  float* sums = (float*)(ws + WS_SUMS);
  float* hbuf = (float*)(ws + WS_HBUF);
  float* c0   = (float*)(ws + WS_C0);
  int*   ctrs = (int*)  (ws + WS_CTRS);
  float* pp   = (float*)(ws + WS_PP);

  hipMemsetAsync(ctrs, 0, GRPS * sizeof(int), stream);  // barrier counters zeroed every call
  k_segsum<<<NB, 256, 0, stream>>>(x, lens, sums);
  k_init  <<<NB, 256, 0, stream>>>(sums, w1h, w2h, w1c, w2c, hbuf, c0);
  k_lstm  <<<NB, 256, 0, stream>>>(x, lens, Wih, Whh, bih, bhh, c0, hbuf, pp, ctrs);
  k_out   <<<NB, 256, 0, stream>>>(pp, lens, fcW, fcb, out);
}